// Round 4
// baseline (166.661 us; speedup 1.0000x reference)
//
#include <hip/hip_runtime.h>
#include <math.h>

// Problem constants (B=8, T=4096, D=256, K=1024)
#define NTOK   32768
#define NDIM   256
#define NCODE  1024
#define CHUNK  4096           // f16 per (strip,kc8) chunk: 128 codes x 32 dims = 8 KB

typedef _Float16 f16x8 __attribute__((ext_vector_type(8)));
typedef float    f32x4 __attribute__((ext_vector_type(4)));

// async global->LDS DMA, 16 B per lane; LDS dst is wave-uniform base + lane*16
__device__ __forceinline__ void gld_lds16(const void* g, void* l) {
    __builtin_amdgcn_global_load_lds(
        (const __attribute__((address_space(1))) void*)g,
        (__attribute__((address_space(3))) void*)l, 16, 0, 0);
}

// ---------------------------------------------------------------------------
// Prep: split codebook (fp32) into f16 hi/lo planes, blocked k-major layout.
// Within-chunk layout (bank-conflict-free for main kernel's ds_read_b128,
// verified round 1: conflicts 4.2M -> 2K):
//   chunk = (strip = row/128, kc8 = dim/32); within chunk:
//   off_f16 = (r>>4)*512 + (g&3)*128 + (r&15)*8     (r = row%128, g&3 = k-quad)
// A wave's b128 read of one 16-row tile is a sequential 1 KB region.
// Plus exact fp32 row norms. ~1 MB total.
// ---------------------------------------------------------------------------
__global__ __launch_bounds__(256) void prep_cb(
        const float* __restrict__ cb,
        _Float16* __restrict__ ch, _Float16* __restrict__ cl,
        float* __restrict__ csq) {
    const int L   = blockIdx.x * 256 + threadIdx.x;   // 0..32767
    const int row = L >> 5;                           // code 0..1023
    const int g   = L & 31;                           // 8-elem group in 256 dims

    const float* src = cb + (size_t)row * NDIM + g * 8;
    float4 a0 = *(const float4*)src;
    float4 a1 = *(const float4*)(src + 4);
    float v[8] = {a0.x, a0.y, a0.z, a0.w, a1.x, a1.y, a1.z, a1.w};
    f16x8 hi, lo;
    float s = 0.f;
    #pragma unroll
    for (int e = 0; e < 8; ++e) {
        _Float16 h = (_Float16)v[e];
        hi[e] = h;
        lo[e] = (_Float16)(v[e] - (float)h);
        s += v[e] * v[e];
    }
    const int r = row & 127;
    const size_t dst = (size_t)((row >> 7) * 8 + (g >> 2)) * CHUNK
                     + (r >> 4) * 512 + (g & 3) * 128 + (r & 15) * 8;
    *(f16x8*)&ch[dst] = hi;
    *(f16x8*)&cl[dst] = lo;
    #pragma unroll
    for (int off = 16; off > 0; off >>= 1) s += __shfl_down(s, off, 32);
    if ((threadIdx.x & 31) == 0) csq[row] = s;
}

// ---------------------------------------------------------------------------
// Main: A-stationary fused VQ with REGISTER double-buffered B fragments
// (T14 issue-early/consume-late applied to LDS->reg: phase p issues ds_reads
// for chunk p+1 into f[(p+1)&1] and MFMAs chunk p from f[p&1], so LDS read
// latency hides under the MFMA cluster instead of serializing before it —
// rounds 0/2/3 all tied at ~66us/31% MfmaUtil because this serial chain,
// not the staging schedule, was the bottleneck).
// 64 tokens/block, 256 threads = 4 waves (2x2 my,nx grid); ring of 4 chunk
// slots (64 KB) + 4 KB csq -> 68 KB LDS, 2 blocks/CU. VGPR ~240 (<=256 is
// free at 8 waves/CU per the 64/128/256 occupancy thresholds).
// Per phase: {stage chunk p+4 -> slot p&3 | vmcnt(12) | s_barrier |
//             ds_read chunk p+1 -> FB | 24 MFMA on FA | lgkmcnt(0) |
//             s_barrier}.
// barrier1: all waves' stage(p+1) drained before reads of slot (p+1)&3.
// lgkm0+barrier2: all waves' reads of slot (p+1)&3 done before next phase
// stages chunk p+5 into that slot. vmcnt never 0 mid-loop (12/8/4/0 tail).
// csq lives in LDS so the VMEM ledger holds ONLY staging ops.
// 3-pass f16 MFMA (ah.bh + al.bh + ah.bl); per-lane running argmin/strip;
// per-strip acc zero via zero-C on the strip's first MFMA pass.
// Layouts (verified): A/B frag [row=lane&15][k=(lane>>4)*8+j]; D col=lane&15,
// row=(lane>>4)*4+reg.
// ---------------------------------------------------------------------------

// Stage chunk c (hi+lo, 16 KB) into slot sl: 4 DMA ops per wave (vmcnt +4).
#define STAGE(c, sl) do {                                                    \
    const size_t _s = (size_t)(c) * CHUNK + w * 1024 + lane * 8;             \
    const int    _d = w * 1024 + lane * 8;                                   \
    gld_lds16(ch + _s,       &Bs[sl][0][_d]);                                \
    gld_lds16(ch + _s + 512, &Bs[sl][0][_d + 512]);                          \
    gld_lds16(cl + _s,       &Bs[sl][1][_d]);                                \
    gld_lds16(cl + _s + 512, &Bs[sl][1][_d + 512]);                          \
} while (0)

// One phase. ph = 0..7 static (global chunk p = S*8+ph; slot = ph&3 since
// S*8 % 4 == 0). FAH/FAL: frags MFMA'd (chunk p). FBH/FBL: frags loaded
// (chunk p+1, slot (ph+1)&3). DOSTAGE/WK/FIRSTZ/DOREAD compile-time.
#define PHASE(ph, S, FAH, FAL, FBH, FBL, DOSTAGE, WK, FIRSTZ, DOREAD) do {   \
    if (DOSTAGE) STAGE((S) * 8 + (ph) + 4, (ph) & 3);                        \
    asm volatile("s_waitcnt vmcnt(" #WK ")" ::: "memory");                   \
    __builtin_amdgcn_s_barrier();                                            \
    if (DOREAD) {                                                            \
        _Pragma("unroll")                                                    \
        for (int _t = 0; _t < 4; ++_t) {                                     \
            FBH[_t] = *(const f16x8*)&Bs[((ph) + 1) & 3][0][boff[_t]];       \
            FBL[_t] = *(const f16x8*)&Bs[((ph) + 1) & 3][1][boff[_t]];       \
        }                                                                    \
    }                                                                        \
    __builtin_amdgcn_s_setprio(1);                                           \
    _Pragma("unroll")                                                        \
    for (int _mt = 0; _mt < 2; ++_mt)                                        \
        _Pragma("unroll")                                                    \
        for (int _t = 0; _t < 4; ++_t) {                                     \
            acc[_mt][_t] = __builtin_amdgcn_mfma_f32_16x16x32_f16(           \
                ah[_mt][(ph)], FAH[_t],                                      \
                (FIRSTZ) ? zz : acc[_mt][_t], 0, 0, 0);                      \
            acc[_mt][_t] = __builtin_amdgcn_mfma_f32_16x16x32_f16(           \
                al[_mt][(ph)], FAH[_t], acc[_mt][_t], 0, 0, 0);              \
            acc[_mt][_t] = __builtin_amdgcn_mfma_f32_16x16x32_f16(           \
                ah[_mt][(ph)], FAL[_t], acc[_mt][_t], 0, 0, 0);              \
        }                                                                    \
    __builtin_amdgcn_s_setprio(0);                                           \
    asm volatile("s_waitcnt lgkmcnt(0)" ::: "memory");                       \
    __builtin_amdgcn_s_barrier();                                            \
} while (0)

// Fold strip S's dot products into the running per-lane argmin (regs + LDS
// csq reads only -- no VMEM, vmcnt ledger untouched).
#define FOLD(S) do {                                                         \
    float cs[4];                                                             \
    _Pragma("unroll")                                                        \
    for (int _t = 0; _t < 4; ++_t)                                           \
        cs[_t] = csq_lds[(S) * 128 + (nx * 4 + _t) * 16 + lr];               \
    _Pragma("unroll")                                                        \
    for (int _mt = 0; _mt < 2; ++_mt)                                        \
        _Pragma("unroll")                                                    \
        for (int _r = 0; _r < 4; ++_r)                                       \
            _Pragma("unroll")                                                \
            for (int _t = 0; _t < 4; ++_t) {                                 \
                float _v = cs[_t] - 2.0f * acc[_mt][_t][_r];                 \
                int   _n = (S) * 128 + (nx * 4 + _t) * 16 + lr;              \
                if (_v < bv[_mt][_r] ||                                      \
                    (_v == bv[_mt][_r] && _n < bi[_mt][_r])) {               \
                    bv[_mt][_r] = _v; bi[_mt][_r] = _n;                      \
                }                                                            \
            }                                                                \
} while (0)

__global__ __launch_bounds__(256, 2) void vq_main(
        const float* __restrict__ z,
        const _Float16* __restrict__ ch, const _Float16* __restrict__ cl,
        const float* __restrict__ csq, const float* __restrict__ cb,
        float* __restrict__ zq, float* __restrict__ io) {
    // ring of 4 chunk-slots x {hi,lo} x 8 KB = 64 KB, + 4 KB csq -> 68 KB
    __shared__ _Float16 Bs[4][2][4096];
    __shared__ float    csq_lds[1024];

    const int tid  = threadIdx.x;
    const int w    = tid >> 6;
    const int lane = tid & 63;
    const int quad = lane >> 4, lr = lane & 15;
    const int my   = w >> 1, nx = w & 1;       // 2 x 2 wave grid
    const int m0   = blockIdx.x * 64;

    // ---- load my 2 m-tiles of z, split into hi/lo register frags ----
    // A-frag for (mt, kc8): A[m = my*32 + mt*16 + lr][k = kc8*32 + quad*8 + j]
    f16x8 ah[2][8], al[2][8];
    #pragma unroll
    for (int mt = 0; mt < 2; ++mt) {
        const float* zp = z + (size_t)(m0 + my * 32 + mt * 16 + lr) * NDIM
                        + quad * 8;
        #pragma unroll
        for (int c = 0; c < 8; ++c) {
            float4 a0 = *(const float4*)(zp + c * 32);
            float4 a1 = *(const float4*)(zp + c * 32 + 4);
            float v[8] = {a0.x, a0.y, a0.z, a0.w, a1.x, a1.y, a1.z, a1.w};
            #pragma unroll
            for (int e = 0; e < 8; ++e) {
                _Float16 h = (_Float16)v[e];
                ah[mt][c][e] = h;
                al[mt][c][e] = (_Float16)(v[e] - (float)h);
            }
        }
    }

    // ---- prologue DMA: csq table + chunk slots 0..3 (17 vmem ops) ----
    gld_lds16(csq + tid * 4, &csq_lds[tid * 4]);
    STAGE(0, 0);
    STAGE(1, 1);
    STAGE(2, 2);
    STAGE(3, 3);

    int boff[4];
    #pragma unroll
    for (int t = 0; t < 4; ++t)
        boff[t] = (nx * 4 + t) * 512 + quad * 128 + lr * 8;

    float bv[2][4];
    int   bi[2][4];
    #pragma unroll
    for (int mt = 0; mt < 2; ++mt)
        #pragma unroll
        for (int r = 0; r < 4; ++r) { bv[mt][r] = INFINITY; bi[mt][r] = 0x7fffffff; }

    const f32x4 zz = (f32x4){0.f, 0.f, 0.f, 0.f};
    f32x4 acc[2][4];
    #pragma unroll
    for (int mt = 0; mt < 2; ++mt)
        #pragma unroll
        for (int t = 0; t < 4; ++t) acc[mt][t] = zz;

    // One-time full drain -> clean vmcnt ledger at loop entry (slots 0..3
    // resident). Steady-state in-flight rebuilds over phases 0..2; phase-p
    // vmcnt(12) first binds at p=3 (drains stage(4)), exactly when chunk 4
    // is first read.
    asm volatile("s_waitcnt vmcnt(0)" ::: "memory");
    __syncthreads();

    // prologue fragment read: chunk 0 -> f0 (lgkm wait auto-inserted before
    // first MFMA use)
    f16x8 f0h[4], f0l[4], f1h[4], f1l[4];
    #pragma unroll
    for (int t = 0; t < 4; ++t) {
        f0h[t] = *(const f16x8*)&Bs[0][0][boff[t]];
        f0l[t] = *(const f16x8*)&Bs[0][1][boff[t]];
    }

    // ---- main loop: strips 0..6 uniform, strip 7 peeled for drain tail ----
    // Phase p (= S*8+ph): MFMA chunk p from f[p&1], read chunk p+1 -> f[~p&1].
    for (int s = 0; s < 7; ++s) {
        PHASE(0, s, f0h, f0l, f1h, f1l, 1, 12, 1, 1);
        PHASE(1, s, f1h, f1l, f0h, f0l, 1, 12, 0, 1);
        PHASE(2, s, f0h, f0l, f1h, f1l, 1, 12, 0, 1);
        PHASE(3, s, f1h, f1l, f0h, f0l, 1, 12, 0, 1);
        PHASE(4, s, f0h, f0l, f1h, f1l, 1, 12, 0, 1);
        PHASE(5, s, f1h, f1l, f0h, f0l, 1, 12, 0, 1);
        PHASE(6, s, f0h, f0l, f1h, f1l, 1, 12, 0, 1);
        PHASE(7, s, f1h, f1l, f0h, f0l, 1, 12, 0, 1);
        FOLD(s);
    }
    {
        const int s = 7;
        PHASE(0, s, f0h, f0l, f1h, f1l, 1, 12, 1, 1);   // stages chunk 60
        PHASE(1, s, f1h, f1l, f0h, f0l, 1, 12, 0, 1);   // stages chunk 61
        PHASE(2, s, f0h, f0l, f1h, f1l, 1, 12, 0, 1);   // stages chunk 62
        PHASE(3, s, f1h, f1l, f0h, f0l, 1, 12, 0, 1);   // stages chunk 63
        PHASE(4, s, f0h, f0l, f1h, f1l, 0,  8, 0, 1);   // drain s61
        PHASE(5, s, f1h, f1l, f0h, f0l, 0,  4, 0, 1);   // drain s62
        PHASE(6, s, f0h, f0l, f1h, f1l, 0,  0, 0, 1);   // drain s63
        PHASE(7, s, f1h, f1l, f0h, f0l, 0,  0, 0, 0);   // last MFMA, no read
        FOLD(7);
    }

    // ---- butterfly over the 16 lanes sharing each row ----
    #pragma unroll
    for (int msk = 1; msk < 16; msk <<= 1)
        #pragma unroll
        for (int mt = 0; mt < 2; ++mt)
            #pragma unroll
            for (int r = 0; r < 4; ++r) {
                float ov = __shfl_xor(bv[mt][r], msk, 64);
                int   oi = __shfl_xor(bi[mt][r], msk, 64);
                if (ov < bv[mt][r] || (ov == bv[mt][r] && oi < bi[mt][r])) {
                    bv[mt][r] = ov; bi[mt][r] = oi;
                }
            }

    __syncthreads();                         // done with Bs; reuse as scratch
    float* sval  = (float*)&Bs[0][0][0];     // [64][2]
    int*   sidx  = (int*)&Bs[0][0][512];     // [64][2]
    int*   bestS = (int*)&Bs[0][0][1024];    // [64]

    if (lr == 0) {
        #pragma unroll
        for (int mt = 0; mt < 2; ++mt)
            #pragma unroll
            for (int r = 0; r < 4; ++r) {
                int row = my * 32 + mt * 16 + quad * 4 + r;   // 0..63
                sval[row * 2 + nx] = bv[mt][r];
                sidx[row * 2 + nx] = bi[mt][r];
            }
    }
    __syncthreads();

    if (tid < 64) {
        float v0 = sval[tid * 2], v1 = sval[tid * 2 + 1];
        int   i0 = sidx[tid * 2], i1 = sidx[tid * 2 + 1];
        bool take1 = (v1 < v0) || (v1 == v0 && i1 < i0);
        int best = take1 ? i1 : i0;
        bestS[tid] = best;
        io[m0 + tid] = (float)best;
    }
    __syncthreads();

    // ---- gather z_q: 64 rows x 1 KB from cb (L2-hot), coalesced float4 ----
    const int tr = tid >> 4, tc = tid & 15;
    #pragma unroll
    for (int p = 0; p < 4; ++p) {
        int row = p * 16 + tr;
        const float* src = cb + (size_t)bestS[row] * NDIM;
        float*       dst = zq + (size_t)(m0 + row) * NDIM;
        #pragma unroll
        for (int q = 0; q < 4; ++q) {
            int col = q * 64 + tc * 4;
            *(float4*)&dst[col] = *(const float4*)&src[col];
        }
    }
}

// ---------------------------------------------------------------------------
extern "C" void kernel_launch(void* const* d_in, const int* in_sizes, int n_in,
                              void* d_out, int out_size, void* d_ws, size_t ws_size,
                              hipStream_t stream) {
    const float* z  = (const float*)d_in[0];
    const float* cb = (const float*)d_in[1];

    float* zq = (float*)d_out;                        // 32768*256 floats
    float* io = (float*)d_out + (size_t)NTOK * NDIM;  // 32768 floats (indices)

    _Float16* ch  = (_Float16*)d_ws;                  // 0.5 MB
    _Float16* cl  = ch + (size_t)NCODE * NDIM;        // 0.5 MB
    float*    csq = (float*)(cl + (size_t)NCODE * NDIM);  // 4 KB

    prep_cb<<<NCODE * 32 / 256, 256, 0, stream>>>(cb, ch, cl, csq);

    vq_main<<<NTOK / 64, 256, 0, stream>>>(z, ch, cl, csq, cb, zq, io);
}

// Round 5
// 133.184 us; speedup vs baseline: 1.2514x; 1.2514x over previous
//
#include <hip/hip_runtime.h>
#include <math.h>

// Problem constants (B=8, T=4096, D=256, K=1024)
#define NTOK   32768
#define NDIM   256
#define NCODE  1024
#define CHUNK  4096           // f16 per (strip,kc8) chunk: 128 codes x 32 dims = 8 KB

typedef _Float16 f16x8 __attribute__((ext_vector_type(8)));
typedef float    f32x4 __attribute__((ext_vector_type(4)));

// ---------------------------------------------------------------------------
// Prep: split codebook (fp32) into f16 hi/lo planes, blocked k-major layout.
//   chunk = (strip = row/128, kc8 = dim/32); within chunk:
//   off_f16 = (r>>4)*512 + (g&3)*128 + (r&15)*8     (r = row%128, g&3 = k-quad)
// One MFMA B-fragment (16 codes x 8 dims) is a contiguous 1 KB region, so a
// wave's 64-lane 16B/lane global load of it is perfectly coalesced.
// Plus exact fp32 row norms. ~1 MB total (L2-resident everywhere).
// ---------------------------------------------------------------------------
__global__ __launch_bounds__(256) void prep_cb(
        const float* __restrict__ cb,
        _Float16* __restrict__ ch, _Float16* __restrict__ cl,
        float* __restrict__ csq) {
    const int L   = blockIdx.x * 256 + threadIdx.x;   // 0..32767
    const int row = L >> 5;                           // code 0..1023
    const int g   = L & 31;                           // 8-elem group in 256 dims

    const float* src = cb + (size_t)row * NDIM + g * 8;
    float4 a0 = *(const float4*)src;
    float4 a1 = *(const float4*)(src + 4);
    float v[8] = {a0.x, a0.y, a0.z, a0.w, a1.x, a1.y, a1.z, a1.w};
    f16x8 hi, lo;
    float s = 0.f;
    #pragma unroll
    for (int e = 0; e < 8; ++e) {
        _Float16 h = (_Float16)v[e];
        hi[e] = h;
        lo[e] = (_Float16)(v[e] - (float)h);
        s += v[e] * v[e];
    }
    const int r = row & 127;
    const size_t dst = (size_t)((row >> 7) * 8 + (g >> 2)) * CHUNK
                     + (r >> 4) * 512 + (g & 3) * 128 + (r & 15) * 8;
    *(f16x8*)&ch[dst] = hi;
    *(f16x8*)&cl[dst] = lo;
    #pragma unroll
    for (int off = 16; off > 0; off >>= 1) s += __shfl_down(s, off, 32);
    if ((threadIdx.x & 31) == 0) csq[row] = s;
}

// ---------------------------------------------------------------------------
// Main: A-stationary fused VQ, NO LDS ring, NO barriers in the main loop.
// Rationale (rounds 0-4): three different LDS staging schedules all tied at
// ~66us / 31% MfmaUtil -- the per-phase barrier lockstep serializes the
// per-CU LDS pipe (~31us of traffic: 32KB DMA-write + 64KB read per chunk
// phase) against the ~25us MFMA floor. Here B-fragments are read directly
// global->reg from the L2-resident 1MB planes (coalesced 1KB per frag-load;
// same-nx waves L1-dedup), so waves are fully independent and MFMA/VMEM
// overlap via TLP + a half-chunk register pipeline.
// Register budget (round-4 lesson: forced 64 frag-regs spilled, <=32 is
// safe): pipeline at 2-tile granularity -> peak frag-live = 2 sets x 16 regs
// = 32, the rounds-2/3 footprint that did not spill.
// 64 tokens/block, 256 threads = 4 waves (2x2 my,nx); LDS only for the tiny
// epilogue scratch. 3-pass f16 MFMA (ah.bh + al.bh + ah.bl); per-lane
// running argmin per strip; acc zeroed via zero-C on ph=0.
// Layouts (verified): A/B frag [row=lane&15][k=(lane>>4)*8+j]; D col=lane&15,
// row=(lane>>4)*4+reg.
// ---------------------------------------------------------------------------

// Load pair `npr` (tiles 2*npr, 2*npr+1) of chunk `c` into frag set (H,L).
// Each frag is a contiguous 1 KB region: 4 global_load_dwordx4 total.
#define LOADP(c, npr, H, L) do {                                             \
    const _Float16* _bh = pbh + (size_t)(c) * 4096 + (npr) * 1024;           \
    const _Float16* _bl = pbl + (size_t)(c) * 4096 + (npr) * 1024;           \
    H[0] = *(const f16x8*)_bh;                                               \
    H[1] = *(const f16x8*)(_bh + 512);                                       \
    L[0] = *(const f16x8*)_bl;                                               \
    L[1] = *(const f16x8*)(_bl + 512);                                       \
} while (0)

// One pipeline step: issue loads for the NEXT pair (chunk NC, pair NPR) into
// (NH,NL), then MFMA the CURRENT pair (A-chunk ph, tiles 2*pr,2*pr+1) from
// (CH,CL). ph/pr/NPR/FIRSTZ/DOPREF compile-time; NC runtime (address only).
#define STEP(ph, pr, CH, CL, NH, NL, NC, NPR, FIRSTZ, DOPREF) do {           \
    if (DOPREF) LOADP(NC, NPR, NH, NL);                                      \
    __builtin_amdgcn_s_setprio(1);                                           \
    _Pragma("unroll")                                                        \
    for (int _mt = 0; _mt < 2; ++_mt)                                        \
        _Pragma("unroll")                                                    \
        for (int _i = 0; _i < 2; ++_i) {                                     \
            const int _t = (pr) * 2 + _i;                                    \
            acc[_mt][_t] = __builtin_amdgcn_mfma_f32_16x16x32_f16(           \
                ah[_mt][(ph)], CH[_i],                                       \
                (FIRSTZ) ? zz : acc[_mt][_t], 0, 0, 0);                      \
            acc[_mt][_t] = __builtin_amdgcn_mfma_f32_16x16x32_f16(           \
                al[_mt][(ph)], CH[_i], acc[_mt][_t], 0, 0, 0);               \
            acc[_mt][_t] = __builtin_amdgcn_mfma_f32_16x16x32_f16(           \
                ah[_mt][(ph)], CL[_i], acc[_mt][_t], 0, 0, 0);               \
        }                                                                    \
    __builtin_amdgcn_s_setprio(0);                                           \
} while (0)

// 16 steps of strip s (chunks s*8 .. s*8+7), PA/PB alternating; the final
// step prefetches the next strip's first pair (unless LASTPREF==0).
#define STRIP(s, LASTPREF) do {                                              \
    const int _gb = (s) * 8;                                                 \
    STEP(0, 0, PAh, PAl, PBh, PBl, _gb + 0, 1, 1, 1);                        \
    STEP(0, 1, PBh, PBl, PAh, PAl, _gb + 1, 0, 1, 1);                        \
    STEP(1, 0, PAh, PAl, PBh, PBl, _gb + 1, 1, 0, 1);                        \
    STEP(1, 1, PBh, PBl, PAh, PAl, _gb + 2, 0, 0, 1);                        \
    STEP(2, 0, PAh, PAl, PBh, PBl, _gb + 2, 1, 0, 1);                        \
    STEP(2, 1, PBh, PBl, PAh, PAl, _gb + 3, 0, 0, 1);                        \
    STEP(3, 0, PAh, PAl, PBh, PBl, _gb + 3, 1, 0, 1);                        \
    STEP(3, 1, PBh, PBl, PAh, PAl, _gb + 4, 0, 0, 1);                        \
    STEP(4, 0, PAh, PAl, PBh, PBl, _gb + 4, 1, 0, 1);                        \
    STEP(4, 1, PBh, PBl, PAh, PAl, _gb + 5, 0, 0, 1);                        \
    STEP(5, 0, PAh, PAl, PBh, PBl, _gb + 5, 1, 0, 1);                        \
    STEP(5, 1, PBh, PBl, PAh, PAl, _gb + 6, 0, 0, 1);                        \
    STEP(6, 0, PAh, PAl, PBh, PBl, _gb + 6, 1, 0, 1);                        \
    STEP(6, 1, PBh, PBl, PAh, PAl, _gb + 7, 0, 0, 1);                        \
    STEP(7, 0, PAh, PAl, PBh, PBl, _gb + 7, 1, 0, 1);                        \
    STEP(7, 1, PBh, PBl, PAh, PAl, _gb + 8, 0, 0, LASTPREF);                 \
} while (0)

// Fold strip s into the running per-lane argmin. csq is L1/L2-hot.
#define FOLD(S) do {                                                         \
    float cs[4];                                                             \
    _Pragma("unroll")                                                        \
    for (int _t = 0; _t < 4; ++_t)                                           \
        cs[_t] = csq[(S) * 128 + (nx * 4 + _t) * 16 + lr];                   \
    _Pragma("unroll")                                                        \
    for (int _mt = 0; _mt < 2; ++_mt)                                        \
        _Pragma("unroll")                                                    \
        for (int _r = 0; _r < 4; ++_r)                                       \
            _Pragma("unroll")                                                \
            for (int _t = 0; _t < 4; ++_t) {                                 \
                float _v = cs[_t] - 2.0f * acc[_mt][_t][_r];                 \
                int   _n = (S) * 128 + (nx * 4 + _t) * 16 + lr;              \
                if (_v < bv[_mt][_r] ||                                      \
                    (_v == bv[_mt][_r] && _n < bi[_mt][_r])) {               \
                    bv[_mt][_r] = _v; bi[_mt][_r] = _n;                      \
                }                                                            \
            }                                                                \
} while (0)

__global__ __launch_bounds__(256, 2) void vq_main(
        const float* __restrict__ z,
        const _Float16* __restrict__ ch, const _Float16* __restrict__ cl,
        const float* __restrict__ csq, const float* __restrict__ cb,
        float* __restrict__ zq, float* __restrict__ io) {
    __shared__ float sval[128];   // epilogue scratch only (~1.3 KB)
    __shared__ int   sidx[128];
    __shared__ int   bestS[64];

    const int tid  = threadIdx.x;
    const int w    = tid >> 6;
    const int lane = tid & 63;
    const int quad = lane >> 4, lr = lane & 15;
    const int my   = w >> 1, nx = w & 1;       // 2 x 2 wave grid
    const int m0   = blockIdx.x * 64;

    // ---- load my 2 m-tiles of z, split into hi/lo register frags ----
    // A-frag for (mt, kc8): A[m = my*32 + mt*16 + lr][k = kc8*32 + quad*8 + j]
    f16x8 ah[2][8], al[2][8];
    #pragma unroll
    for (int mt = 0; mt < 2; ++mt) {
        const float* zp = z + (size_t)(m0 + my * 32 + mt * 16 + lr) * NDIM
                        + quad * 8;
        #pragma unroll
        for (int c = 0; c < 8; ++c) {
            float4 a0 = *(const float4*)(zp + c * 32);
            float4 a1 = *(const float4*)(zp + c * 32 + 4);
            float v[8] = {a0.x, a0.y, a0.z, a0.w, a1.x, a1.y, a1.z, a1.w};
            #pragma unroll
            for (int e = 0; e < 8; ++e) {
                _Float16 h = (_Float16)v[e];
                ah[mt][c][e] = h;
                al[mt][c][e] = (_Float16)(v[e] - (float)h);
            }
        }
    }

    // per-wave B base pointers (f16 units): frag(c, t) lives at
    // pb? + c*4096 + t*512  (t = nx*4 + tile; fold nx into the base)
    const _Float16* pbh = ch + nx * 2048 + quad * 128 + lr * 8;
    const _Float16* pbl = cl + nx * 2048 + quad * 128 + lr * 8;

    float bv[2][4];
    int   bi[2][4];
    #pragma unroll
    for (int mt = 0; mt < 2; ++mt)
        #pragma unroll
        for (int r = 0; r < 4; ++r) { bv[mt][r] = INFINITY; bi[mt][r] = 0x7fffffff; }

    const f32x4 zz = (f32x4){0.f, 0.f, 0.f, 0.f};
    f32x4 acc[2][4];

    // pipeline prologue: first pair of chunk 0 -> PA
    f16x8 PAh[2], PAl[2], PBh[2], PBl[2];
    LOADP(0, 0, PAh, PAl);

    // ---- main loop: no barriers, waves fully independent ----
    for (int s = 0; s < 7; ++s) {
        STRIP(s, 1);
        FOLD(s);
    }
    STRIP(7, 0);
    FOLD(7);

    // ---- butterfly over the 16 lanes sharing each row ----
    #pragma unroll
    for (int msk = 1; msk < 16; msk <<= 1)
        #pragma unroll
        for (int mt = 0; mt < 2; ++mt)
            #pragma unroll
            for (int r = 0; r < 4; ++r) {
                float ov = __shfl_xor(bv[mt][r], msk, 64);
                int   oi = __shfl_xor(bi[mt][r], msk, 64);
                if (ov < bv[mt][r] || (ov == bv[mt][r] && oi < bi[mt][r])) {
                    bv[mt][r] = ov; bi[mt][r] = oi;
                }
            }

    // ---- cross-nx merge + index write + zq gather (LDS scratch) ----
    if (lr == 0) {
        #pragma unroll
        for (int mt = 0; mt < 2; ++mt)
            #pragma unroll
            for (int r = 0; r < 4; ++r) {
                int row = my * 32 + mt * 16 + quad * 4 + r;   // 0..63
                sval[row * 2 + nx] = bv[mt][r];
                sidx[row * 2 + nx] = bi[mt][r];
            }
    }
    __syncthreads();

    if (tid < 64) {
        float v0 = sval[tid * 2], v1 = sval[tid * 2 + 1];
        int   i0 = sidx[tid * 2], i1 = sidx[tid * 2 + 1];
        bool take1 = (v1 < v0) || (v1 == v0 && i1 < i0);
        int best = take1 ? i1 : i0;
        bestS[tid] = best;
        io[m0 + tid] = (float)best;
    }
    __syncthreads();

    // ---- gather z_q: 64 rows x 1 KB from cb (L2-hot), coalesced float4 ----
    const int tr = tid >> 4, tc = tid & 15;
    #pragma unroll
    for (int p = 0; p < 4; ++p) {
        int row = p * 16 + tr;
        const float* src = cb + (size_t)bestS[row] * NDIM;
        float*       dst = zq + (size_t)(m0 + row) * NDIM;
        #pragma unroll
        for (int q = 0; q < 4; ++q) {
            int col = q * 64 + tc * 4;
            *(float4*)&dst[col] = *(const float4*)&src[col];
        }
    }
}

// ---------------------------------------------------------------------------
extern "C" void kernel_launch(void* const* d_in, const int* in_sizes, int n_in,
                              void* d_out, int out_size, void* d_ws, size_t ws_size,
                              hipStream_t stream) {
    const float* z  = (const float*)d_in[0];
    const float* cb = (const float*)d_in[1];

    float* zq = (float*)d_out;                        // 32768*256 floats
    float* io = (float*)d_out + (size_t)NTOK * NDIM;  // 32768 floats (indices)

    _Float16* ch  = (_Float16*)d_ws;                  // 0.5 MB
    _Float16* cl  = ch + (size_t)NCODE * NDIM;        // 0.5 MB
    float*    csq = (float*)(cl + (size_t)NCODE * NDIM);  // 4 KB

    prep_cb<<<NCODE * 32 / 256, 256, 0, stream>>>(cb, ch, cl, csq);

    vq_main<<<NTOK / 64, 256, 0, stream>>>(z, ch, cl, csq, cb, zq, io);
}